// Round 13
// baseline (141910.742 us; speedup 1.0000x reference)
//
#include <hip/hip_runtime.h>
#include <math.h>

// HierarchicalRecursiveTRM on MI355X — round 13.
// Base = round 12 (84.6ms): 8 teams x (2 batches, 32 WGs), f32 weights in LDS,
// atomic-exchange publication (MALL-resident), tag-embedded f16-pair words,
// GRU hidden under L1, fused 16B polls.
// Change: SINGLE-BARRIER stages with wave-local pack+swap. Row r's gate=unit
// 2r, tanh=unit 2r+1 (adjacent 16-lane units, same wave) -> after intra-unit
// reduce, one __shfl_xor(.,16) pairs (g,T) in-register; even-unit lane 0
// swaps both batches' words. Removes per stage: 2nd WGBAR + exv LDS relay +
// 16-lane serial pack phase. Same for GRU-produce and U-stages.

#define NB   16
#define SEQ  4096
#define TEAMS 8
#define WPT  32
#define BPT  2
#define NTH  256

typedef unsigned long long u64;
typedef unsigned u32x4 __attribute__((ext_vector_type(4)));

__device__ __forceinline__ float fexp(float v){ return __builtin_amdgcn_exp2f(v*1.44269504089f); }
__device__ __forceinline__ float sigf(float v){ return __builtin_amdgcn_rcpf(1.f + fexp(-v)); }
__device__ __forceinline__ float ftanh(float v){ return 2.f*sigf(2.f*v) - 1.f; }

// producer: no-return atomic swap — commits at the coherence-point atomic unit
__device__ __forceinline__ void swpw(u64* p, u64 v){
  (void)__hip_atomic_exchange(p, v, __ATOMIC_RELAXED, __HIP_MEMORY_SCOPE_AGENT);
}
// consumer: relaxed agent load (single-word poll, U-stages)
__device__ __forceinline__ u64 ldw(const u64* p){
  return __hip_atomic_load(p, __ATOMIC_RELAXED, __HIP_MEMORY_SCOPE_AGENT);
}

// f16x2 pack/unpack
typedef _Float16 h2f __attribute__((ext_vector_type(2)));
typedef __fp16   h2p __attribute__((ext_vector_type(2)));
union H2U { h2f f; h2p p; unsigned u; };
__device__ __forceinline__ unsigned pk2(float lo, float hi){
  H2U t; t.p = __builtin_amdgcn_cvt_pkrtz(lo, hi); return t.u;
}
__device__ __forceinline__ float2 upk2(unsigned w){
  H2U t; t.u = w; float2 r; r.x = (float)t.f.x; r.y = (float)t.f.y; return r;
}
__device__ __forceinline__ u64 packh(float lo, float hi, unsigned tag){
  return ((u64)tag<<32) | (u64)pk2(lo, hi);
}

// fused 16B poll: two adjacent tagged words in ONE dwordx4 sc0sc1 load
__device__ __forceinline__ void poll2x(const u64* p, unsigned tag,
                                       unsigned &lo0, unsigned &lo1){
  u32x4 v;
  for(;;){
    asm volatile("global_load_dwordx4 %0, %1, off sc0 sc1\n\ts_waitcnt vmcnt(0)"
                 : "=&v"(v) : "v"(p) : "memory");
    if (v.y >= tag && v.w >= tag) break;
    __builtin_amdgcn_s_sleep(1);
  }
  lo0 = v.x; lo1 = v.z;
}

// Raw WG barrier: LDS ordering only, no vmcnt drain (swaps fly free).
#define WGBAR() asm volatile("s_waitcnt lgkmcnt(0)\n\ts_barrier" ::: "memory")

extern "C" __global__ __launch_bounds__(NTH, 1)
void trm_kernel(const float* __restrict__ x,   const float* __restrict__ h0,
                const float* __restrict__ wih, const float* __restrict__ whh,
                const float* __restrict__ bih, const float* __restrict__ bhh,
                const float* __restrict__ Lgw, const float* __restrict__ Lgb,
                const float* __restrict__ Ltw, const float* __restrict__ Ltb,
                const float* __restrict__ Luw, const float* __restrict__ Lub,
                const float* __restrict__ Hgw, const float* __restrict__ Hgb,
                const float* __restrict__ Htw, const float* __restrict__ Htb,
                const float* __restrict__ Huw, const float* __restrict__ Hub,
                float* __restrict__ out, u64* __restrict__ act_base)
{
  const int team = blockIdx.x & (TEAMS-1);
  const int j    = blockIdx.x / TEAMS;       // 0..31 slice id within team
  const int tid  = threadIdx.x;

  // GRU r/z rows interleaved: wgRZ[2r]=reset row, wgRZ[2r+1]=update row
  __shared__ float wgRZ[16][520];
  __shared__ float wgX[8][264];
  __shared__ float wgN[8][264];
  __shared__ float wclG[8][520], wclT[8][520];
  __shared__ float wchG[8][520], wchT[8][520];
  __shared__ float wul[8][264],  wuh[8][264];
  __shared__ float xst [BPT][256];
  __shared__ float st_o [BPT][256];
  __shared__ float st_zh[BPT][256];
  __shared__ float st_zl[BPT][256];
  __shared__ float st_h [BPT][256];
  __shared__ float bR[8],bZ[8],bX[8],bN[8],bCLg[8],bCLt[8],bCHg[8],bCHt[8],bUL[8],bUH[8];

  // ---------- one-time weight staging ----------
  {
    const int k = tid;
    for (int r=0;r<8;r++){
      const int nr = j*8+r;
      wgRZ[2*r][k]       = wih[(size_t)nr*256+k];        // reset row
      wgRZ[2*r][256+k]   = whh[(size_t)nr*256+k];
      wgRZ[2*r+1][k]     = wih[(size_t)(256+nr)*256+k];  // update row
      wgRZ[2*r+1][256+k] = whh[(size_t)(256+nr)*256+k];
      wgX[r][k] = wih[(size_t)(512+nr)*256+k];
      wgN[r][k] = whh[(size_t)(512+nr)*256+k];
      wclG[r][k] = Lgw[(size_t)nr*512+k];  wclG[r][256+k] = Lgw[(size_t)nr*512+256+k];
      wclT[r][k] = Ltw[(size_t)nr*512+k];  wclT[r][256+k] = Ltw[(size_t)nr*512+256+k];
      wchG[r][k] = Hgw[(size_t)nr*512+k];  wchG[r][256+k] = Hgw[(size_t)nr*512+256+k];
      wchT[r][k] = Htw[(size_t)nr*512+k];  wchT[r][256+k] = Htw[(size_t)nr*512+256+k];
      wul[r][k] = Luw[(size_t)nr*256+k];
      wuh[r][k] = Huw[(size_t)nr*256+k];
    }
    if (tid<8){
      const int nr = j*8+tid;
      bR[tid]  = bih[nr]     + bhh[nr];
      bZ[tid]  = bih[256+nr] + bhh[256+nr];
      bX[tid]  = bih[512+nr];
      bN[tid]  = bhh[512+nr];
      bCLg[tid]= Lgb[nr];  bCLt[tid]= Ltb[nr];
      bCHg[tid]= Hgb[nr];  bCHt[tid]= Htb[nr];
      bUL[tid] = Lub[nr];  bUH[tid] = Hub[nr];
    }
    st_h[0][tid]  = h0[(team*BPT+0)*256+tid];
    st_h[1][tid]  = h0[(team*BPT+1)*256+tid];
    st_o[0][tid]  = 0.f;  st_o[1][tid]  = 0.f;
    st_zh[0][tid] = 0.f;  st_zh[1][tid] = 0.f;
    st_zl[0][tid] = 0.f;  st_zl[1][tid] = 0.f;
    xst[0][tid] = x[((size_t)(team*BPT+0)*SEQ + 0)*256 + tid];
    xst[1][tid] = x[((size_t)(team*BPT+1)*SEQ + 0)*256 + tid];
  }
  __syncthreads();

  u64* actT = act_base + (size_t)team*4096;   // [0,2048): 2 refine bufs; [2048,3072): GRU ring
  u64* gb   = actT + 2048;
  unsigned kst = 0;
  const bool wr0 = (j == 0);

  // GRU produce for step `step` (reads xst=x(step), st_h=h(step-1)). Wave-local:
  // unit 2r = reset row + xn row; unit 2r+1 = update row + hn row.
  auto gru_produce = [&](int step){
    const unsigned gt = (unsigned)step + 1u;
    u64* g = gb + (size_t)(step & 1)*512;
    const int u = tid>>4, kk = tid&15, r = u>>1;
    const bool odd = (u&1);
    float a0=0.f, a1=0.f;        // pass1: r-row (even) / z-row (odd), K=512
    {
      const float* wr = wgRZ[u];
      #pragma unroll
      for (int i=0;i<16;i++){
        const float w = wr[kk+16*i];
        a0 += w*xst[0][kk+16*i];
        a1 += w*xst[1][kk+16*i];
      }
      #pragma unroll
      for (int i=0;i<16;i++){
        const float w = wr[256+kk+16*i];
        a0 += w*st_h[0][kk+16*i];
        a1 += w*st_h[1][kk+16*i];
      }
      a0 += __shfl_xor(a0,1); a0 += __shfl_xor(a0,2); a0 += __shfl_xor(a0,4); a0 += __shfl_xor(a0,8);
      a1 += __shfl_xor(a1,1); a1 += __shfl_xor(a1,2); a1 += __shfl_xor(a1,4); a1 += __shfl_xor(a1,8);
    }
    float c0=0.f, c1=0.f;        // pass2: xn row (even, src=x) / hn row (odd, src=h), K=256
    {
      const float* wr = odd? wgN[r] : wgX[r];
      float (*src)[256] = odd? st_h : xst;
      #pragma unroll
      for (int i=0;i<16;i++){
        const float w = wr[kk+16*i];
        c0 += w*src[0][kk+16*i];
        c1 += w*src[1][kk+16*i];
      }
      c0 += __shfl_xor(c0,1); c0 += __shfl_xor(c0,2); c0 += __shfl_xor(c0,4); c0 += __shfl_xor(c0,8);
      c1 += __shfl_xor(c1,1); c1 += __shfl_xor(c1,2); c1 += __shfl_xor(c1,4); c1 += __shfl_xor(c1,8);
    }
    const float ta0 = __shfl_xor(a0,16), ta1 = __shfl_xor(a1,16);   // partner unit's sums
    const float tc0 = __shfl_xor(c0,16), tc1 = __shfl_xor(c1,16);
    if (!odd && kk==0){          // even-unit lane 0: full gate math, both batches
      const float rg0 = sigf(a0 + bR[r]);
      const float zg0 = sigf(ta0 + bZ[r]);
      const float ng0 = ftanh(c0 + bX[r] + rg0*(tc0 + bN[r]));
      const float rg1 = sigf(a1 + bR[r]);
      const float zg1 = sigf(ta1 + bZ[r]);
      const float ng1 = ftanh(c1 + bX[r] + rg1*(tc1 + bN[r]));
      const int n = j*8+r;
      swpw(&g[(size_t)n*2 + 0], packh(ng0, zg0, gt));
      swpw(&g[(size_t)n*2 + 1], packh(ng1, zg1, gt));
    }
  };

  // C-cell: row r: gate=unit 2r, tanh=unit 2r+1 (same wave). K=512=[o|hid].
  auto cstage = [&](float (*WG)[520], float (*WT)[520], float* bG, float* bT,
                    float (*hid)[256], bool wout, bool pg, int tt){
    const unsigned tag = kst + 1u;
    u64* buf = actT + (kst & 1u)*1024;
    WGBAR();                                   // prev-stage state updates visible
    const int u = tid>>4, kk = tid&15, r = u>>1;
    const bool isT = (u&1);
    const float* wr = isT? WT[r] : WG[r];
    float a0=0.f, a1=0.f;
    #pragma unroll
    for (int i=0;i<16;i++){
      const float w = wr[kk+16*i];
      a0 += w*st_o[0][kk+16*i];
      a1 += w*st_o[1][kk+16*i];
    }
    #pragma unroll
    for (int i=0;i<16;i++){
      const float w = wr[256+kk+16*i];
      a0 += w*hid[0][kk+16*i];
      a1 += w*hid[1][kk+16*i];
    }
    a0 += __shfl_xor(a0,1); a0 += __shfl_xor(a0,2); a0 += __shfl_xor(a0,4); a0 += __shfl_xor(a0,8);
    a1 += __shfl_xor(a1,1); a1 += __shfl_xor(a1,2); a1 += __shfl_xor(a1,4); a1 += __shfl_xor(a1,8);
    const float t0 = __shfl_xor(a0,16);        // even lanes receive tanh-unit sums
    const float t1 = __shfl_xor(a1,16);
    if (!isT && kk==0){
      const float g0 = sigf (a0 + bG[r]);
      const float T0 = ftanh(t0 + bT[r]);
      const float g1 = sigf (a1 + bG[r]);
      const float T1 = ftanh(t1 + bT[r]);
      const int n = j*8+r;
      swpw(&buf[(size_t)n*2 + 0], packh(g0, T0, tag));
      swpw(&buf[(size_t)n*2 + 1], packh(g1, T1, tag));
    }
    if (pg) gru_produce(tt+1);                 // hidden under this stage's exchange wait
    unsigned lo0, lo1;
    poll2x(&buf[2*tid], tag, lo0, lo1);
    const float2 gt0 = upk2(lo0);
    const float2 gt1 = upk2(lo1);
    const float o0 = gt0.x*gt0.y + (1.f-gt0.x)*st_o[0][tid];
    const float o1 = gt1.x*gt1.y + (1.f-gt1.x)*st_o[1][tid];
    st_o[0][tid] = o0;
    st_o[1][tid] = o1;
    if (wout && wr0){
      out[((size_t)(team*BPT+0)*SEQ + tt)*256 + tid] = o0;
      out[((size_t)(team*BPT+1)*SEQ + tt)*256 + tid] = o1;
    }
    kst++;
  };

  // U-cell: 8 rows/WG, 32-lane units, K=256 over st_o; wave-local pack+swap.
  auto ustage = [&](float (*W)[264], float* bU, float (*dst)[256]){
    const unsigned tag = kst + 1u;
    u64* buf = actT + (kst & 1u)*1024;
    WGBAR();
    const int u = tid>>5, kk = tid&31;
    const float* wr = W[u];
    float a0=0.f, a1=0.f;
    #pragma unroll
    for (int i=0;i<8;i++){
      const float w = wr[kk+32*i];
      a0 += w*st_o[0][kk+32*i];
      a1 += w*st_o[1][kk+32*i];
    }
    a0 += __shfl_xor(a0,1); a0 += __shfl_xor(a0,2); a0 += __shfl_xor(a0,4); a0 += __shfl_xor(a0,8); a0 += __shfl_xor(a0,16);
    a1 += __shfl_xor(a1,1); a1 += __shfl_xor(a1,2); a1 += __shfl_xor(a1,4); a1 += __shfl_xor(a1,8); a1 += __shfl_xor(a1,16);
    if (kk==0){
      const float v0 = ftanh(a0 + bU[u]);
      const float v1 = ftanh(a1 + bU[u]);
      swpw(&buf[j*8 + u], packh(v0, v1, tag));
    }
    u64 w0;
    for(;;){
      w0 = ldw(&buf[tid]);
      if ((unsigned)(w0>>32) >= tag) break;
      __builtin_amdgcn_s_sleep(1);
    }
    const float2 v = upk2((unsigned)w0);
    dst[0][tid] = v.x;
    dst[1][tid] = v.y;
    kst++;
  };

  // prologue: produce GRU(0) (tag 1, slot 0) from h0 and x(0)
  float px0 = x[((size_t)(team*BPT+0)*SEQ + 1)*256 + tid];
  float px1 = x[((size_t)(team*BPT+1)*SEQ + 1)*256 + tid];
  gru_produce(0);

  #pragma unroll 1
  for (int t=0; t<SEQ; ++t){
    // ---- GRU consume (pre-satisfied poll: produced >=11 stages ago) ----
    {
      WGBAR();                                 // prior U_H matvec reads of st_o done
      u64* g = gb + (size_t)(t & 1)*512;
      unsigned lo0, lo1;
      poll2x(&g[2*tid], (unsigned)(t+1), lo0, lo1);
      const float2 nz0 = upk2(lo0);
      const float2 nz1 = upk2(lo1);
      const float h0v = (1.f-nz0.y)*nz0.x + nz0.y*st_h[0][tid];
      const float h1v = (1.f-nz1.y)*nz1.x + nz1.y*st_h[1][tid];
      st_h[0][tid] = h0v;  st_o[0][tid] = h0v;
      st_h[1][tid] = h1v;  st_o[1][tid] = h1v;
      xst[0][tid] = px0;                       // x(t+1) for GRU produce at L1(t)
      xst[1][tid] = px1;
      if (t+2 < SEQ){
        px0 = x[((size_t)(team*BPT+0)*SEQ + (t+2))*256 + tid];
        px1 = x[((size_t)(team*BPT+1)*SEQ + (t+2))*256 + tid];
      }
      if (t == SEQ-1 && wr0){
        out[(size_t)NB*SEQ*256 + (team*BPT+0)*256 + tid] = h0v;
        out[(size_t)NB*SEQ*256 + (team*BPT+1)*256 + tid] = h1v;
      }
    }
    // ---- refinement: 2 H-cycles of (3x L-cell, U_L, H-cell, U_H) ----
    #pragma unroll 1
    for (int c=0;c<2;c++){
      cstage(wclG,wclT,bCLg,bCLt,st_zh,false,(c==0)&&(t+1<SEQ),t);  // L1 (+GRU(t+1))
      cstage(wclG,wclT,bCLg,bCLt,st_zh,false,false,t);
      cstage(wclG,wclT,bCLg,bCLt,st_zh,false,false,t);
      ustage(wul,bUL,st_zl);
      cstage(wchG,wchT,bCHg,bCHt,st_zl,(c==1),false,t);
      ustage(wuh,bUH,st_zh);
    }
  }
}

extern "C" void kernel_launch(void* const* d_in, const int* in_sizes, int n_in,
                              void* d_out, int out_size, void* d_ws, size_t ws_size,
                              hipStream_t stream)
{
  // ws: per-team 32KB = [2 x 1024 u64 refine bufs | 2 x 512 u64 GRU ring].
  // Zeroed every launch (tags must start below 1; harness poisons 0xAA once).
  (void)hipMemsetAsync(d_ws, 0, (size_t)TEAMS*4096*sizeof(u64), stream);
  u64* act = (u64*)d_ws;

  dim3 grid(TEAMS*WPT), block(NTH);
  hipLaunchKernelGGL(trm_kernel, grid, block, 0, stream,
    (const float*)d_in[0],  (const float*)d_in[1],
    (const float*)d_in[2],  (const float*)d_in[3],
    (const float*)d_in[4],  (const float*)d_in[5],
    (const float*)d_in[6],  (const float*)d_in[7],
    (const float*)d_in[8],  (const float*)d_in[9],
    (const float*)d_in[10], (const float*)d_in[11],
    (const float*)d_in[12], (const float*)d_in[13],
    (const float*)d_in[14], (const float*)d_in[15],
    (const float*)d_in[16], (const float*)d_in[17],
    (float*)d_out, act);
}

// Round 14
// 86043.488 us; speedup vs baseline: 1.6493x; 1.6493x over previous
//
#include <hip/hip_runtime.h>
#include <math.h>

// HierarchicalRecursiveTRM on MI355X — round 14.
// Base = round 12 (84.6ms, proven): 8 teams x (2 batches, 32 WGs), f32 weights
// in LDS, centralized 16-lane swap burst per stage (R13's distributed packing
// regressed 64% — write amplification + scattered arrival), GRU hidden under
// L1, fused 16B polls, tag-embedded f16-pair words.
// Change: exchange medium MALL -> XCD-local L2 for XCD-uniform teams (runtime
// HW_REG_XCC_ID check). Producer: WORKGROUP-scope atomic swap (global_atomic,
// no sc1 -> executes at local L2). Consumer: WORKGROUP-scope fetch_add(0)
// probe (L2 RMW) + MALL dwordx4 load probe each iteration (hedge: if wg-scope
// actually lands at MALL, the load probe carries at R12 speed). Tag-fused 8B
// words make mixed acceptance race-free. Non-uniform teams: exact R12 path.

#define NB   16
#define SEQ  4096
#define TEAMS 8
#define WPT  32
#define BPT  2
#define NTH  256

typedef unsigned long long u64;
typedef unsigned u32x4 __attribute__((ext_vector_type(4)));

__device__ __forceinline__ float fexp(float v){ return __builtin_amdgcn_exp2f(v*1.44269504089f); }
__device__ __forceinline__ float sigf(float v){ return __builtin_amdgcn_rcpf(1.f + fexp(-v)); }
__device__ __forceinline__ float ftanh(float v){ return 2.f*sigf(2.f*v) - 1.f; }

// startup-only agent-scope relaxed helpers (round-3-proven)
__device__ __forceinline__ void st_ag(unsigned* p, unsigned v){
  __hip_atomic_store(p, v, __ATOMIC_RELAXED, __HIP_MEMORY_SCOPE_AGENT);
}
__device__ __forceinline__ unsigned ld_ag(const unsigned* p){
  return __hip_atomic_load(p, __ATOMIC_RELAXED, __HIP_MEMORY_SCOPE_AGENT);
}

// producer: no-return atomic swap. fast -> workgroup scope (L2-executed);
// slow -> agent scope (MALL, R12-proven).
__device__ __forceinline__ void swpw(u64* p, u64 v, bool fast){
  if (fast) (void)__hip_atomic_exchange(p, v, __ATOMIC_RELAXED, __HIP_MEMORY_SCOPE_WORKGROUP);
  else      (void)__hip_atomic_exchange(p, v, __ATOMIC_RELAXED, __HIP_MEMORY_SCOPE_AGENT);
}
// consumer single-word relaxed agent load (R12 slow-path primitive)
__device__ __forceinline__ u64 ldw(const u64* p){
  return __hip_atomic_load(p, __ATOMIC_RELAXED, __HIP_MEMORY_SCOPE_AGENT);
}
// L2 RMW probe
__device__ __forceinline__ u64 rmw(u64* p){
  return __hip_atomic_fetch_add(p, 0ull, __ATOMIC_RELAXED, __HIP_MEMORY_SCOPE_WORKGROUP);
}

// f16x2 pack/unpack
typedef _Float16 h2f __attribute__((ext_vector_type(2)));
typedef __fp16   h2p __attribute__((ext_vector_type(2)));
union H2U { h2f f; h2p p; unsigned u; };
__device__ __forceinline__ unsigned pk2(float lo, float hi){
  H2U t; t.p = __builtin_amdgcn_cvt_pkrtz(lo, hi); return t.u;
}
__device__ __forceinline__ float2 upk2(unsigned w){
  H2U t; t.u = w; float2 r; r.x = (float)t.f.x; r.y = (float)t.f.y; return r;
}
__device__ __forceinline__ u64 packh(float lo, float hi, unsigned tag){
  return ((u64)tag<<32) | (u64)pk2(lo, hi);
}

// dual-probe 2-word poll. fast: L2 RMW pair, then MALL 16B load as hedge.
__device__ __forceinline__ void poll2x(u64* p, unsigned tag, bool fast,
                                       unsigned &lo0, unsigned &lo1){
  if (fast){
    for(;;){
      u64 w0 = rmw(p);
      u64 w1 = rmw(p+1);
      if ((unsigned)(w0>>32) >= tag && (unsigned)(w1>>32) >= tag){
        lo0 = (unsigned)w0; lo1 = (unsigned)w1; return;
      }
      u32x4 v;
      asm volatile("global_load_dwordx4 %0, %1, off sc0 sc1\n\ts_waitcnt vmcnt(0)"
                   : "=&v"(v) : "v"(p) : "memory");
      if (v.y >= tag && v.w >= tag){ lo0 = v.x; lo1 = v.z; return; }
    }
  } else {
    u32x4 v;
    for(;;){
      asm volatile("global_load_dwordx4 %0, %1, off sc0 sc1\n\ts_waitcnt vmcnt(0)"
                   : "=&v"(v) : "v"(p) : "memory");
      if (v.y >= tag && v.w >= tag) break;
      __builtin_amdgcn_s_sleep(1);
    }
    lo0 = v.x; lo1 = v.z;
  }
}

// dual-probe 1-word poll (U-stages)
__device__ __forceinline__ unsigned poll1x(u64* p, unsigned tag, bool fast){
  if (fast){
    for(;;){
      u64 w = rmw(p);
      if ((unsigned)(w>>32) >= tag) return (unsigned)w;
      w = ldw(p);
      if ((unsigned)(w>>32) >= tag) return (unsigned)w;
    }
  } else {
    for(;;){
      u64 w = ldw(p);
      if ((unsigned)(w>>32) >= tag) return (unsigned)w;
      __builtin_amdgcn_s_sleep(1);
    }
  }
}

// Raw WG barrier: LDS ordering only, no vmcnt drain (swaps fly free).
#define WGBAR() asm volatile("s_waitcnt lgkmcnt(0)\n\ts_barrier" ::: "memory")

extern "C" __global__ __launch_bounds__(NTH, 1)
void trm_kernel(const float* __restrict__ x,   const float* __restrict__ h0,
                const float* __restrict__ wih, const float* __restrict__ whh,
                const float* __restrict__ bih, const float* __restrict__ bhh,
                const float* __restrict__ Lgw, const float* __restrict__ Lgb,
                const float* __restrict__ Ltw, const float* __restrict__ Ltb,
                const float* __restrict__ Luw, const float* __restrict__ Lub,
                const float* __restrict__ Hgw, const float* __restrict__ Hgb,
                const float* __restrict__ Htw, const float* __restrict__ Htb,
                const float* __restrict__ Huw, const float* __restrict__ Hub,
                float* __restrict__ out,
                unsigned* __restrict__ flg_base, u64* __restrict__ act_base)
{
  const int team = blockIdx.x & (TEAMS-1);
  const int j    = blockIdx.x / TEAMS;       // 0..31 slice id within team
  const int tid  = threadIdx.x;

  __shared__ float wgRZ[16][520];
  __shared__ float wgX[8][264];
  __shared__ float wgN[8][264];
  __shared__ float wclG[8][520], wclT[8][520];
  __shared__ float wchG[8][520], wchT[8][520];
  __shared__ float wul[8][264],  wuh[8][264];
  __shared__ float xst [BPT][256];
  __shared__ float st_o [BPT][256];
  __shared__ float st_zh[BPT][256];
  __shared__ float st_zl[BPT][256];
  __shared__ float st_h [BPT][256];
  __shared__ float exvA[16][2], exvC[16][2], exvD[16][2];
  __shared__ float bR[8],bZ[8],bX[8],bN[8],bCLg[8],bCLt[8],bCHg[8],bCHt[8],bUL[8],bUH[8];

  // ---------- one-time weight staging ----------
  {
    const int k = tid;
    for (int r=0;r<8;r++){
      const int nr = j*8+r;
      wgRZ[r][k]       = wih[(size_t)nr*256+k];
      wgRZ[r][256+k]   = whh[(size_t)nr*256+k];
      wgRZ[8+r][k]     = wih[(size_t)(256+nr)*256+k];
      wgRZ[8+r][256+k] = whh[(size_t)(256+nr)*256+k];
      wgX[r][k] = wih[(size_t)(512+nr)*256+k];
      wgN[r][k] = whh[(size_t)(512+nr)*256+k];
      wclG[r][k] = Lgw[(size_t)nr*512+k];  wclG[r][256+k] = Lgw[(size_t)nr*512+256+k];
      wclT[r][k] = Ltw[(size_t)nr*512+k];  wclT[r][256+k] = Ltw[(size_t)nr*512+256+k];
      wchG[r][k] = Hgw[(size_t)nr*512+k];  wchG[r][256+k] = Hgw[(size_t)nr*512+256+k];
      wchT[r][k] = Htw[(size_t)nr*512+k];  wchT[r][256+k] = Htw[(size_t)nr*512+256+k];
      wul[r][k] = Luw[(size_t)nr*256+k];
      wuh[r][k] = Huw[(size_t)nr*256+k];
    }
    if (tid<8){
      const int nr = j*8+tid;
      bR[tid]  = bih[nr]     + bhh[nr];
      bZ[tid]  = bih[256+nr] + bhh[256+nr];
      bX[tid]  = bih[512+nr];
      bN[tid]  = bhh[512+nr];
      bCLg[tid]= Lgb[nr];  bCLt[tid]= Ltb[nr];
      bCHg[tid]= Hgb[nr];  bCHt[tid]= Htb[nr];
      bUL[tid] = Lub[nr];  bUH[tid] = Hub[nr];
    }
    st_h[0][tid]  = h0[(team*BPT+0)*256+tid];
    st_h[1][tid]  = h0[(team*BPT+1)*256+tid];
    st_o[0][tid]  = 0.f;  st_o[1][tid]  = 0.f;
    st_zh[0][tid] = 0.f;  st_zh[1][tid] = 0.f;
    st_zl[0][tid] = 0.f;  st_zl[1][tid] = 0.f;
    xst[0][tid] = x[((size_t)(team*BPT+0)*SEQ + 0)*256 + tid];
    xst[1][tid] = x[((size_t)(team*BPT+1)*SEQ + 0)*256 + tid];
  }

  // ---------- startup: publish XCC id, team barrier, pick protocol ----------
  unsigned* flg = flg_base + team*1024;   // 4KB-separated
  unsigned xcc = 0;
  asm volatile("s_getreg_b32 %0, hwreg(HW_REG_XCC_ID)" : "=s"(xcc));
  __syncthreads();
  if (tid == 0) st_ag(flg + j, 0x100u | xcc);
  if (tid < 64){
    const int fl = tid & 31;
    for (;;){
      unsigned v = ld_ag(flg + fl);
      if (__all(v != 0)) break;
      __builtin_amdgcn_s_sleep(8);
    }
  }
  __syncthreads();
  bool fast;
  {
    unsigned v  = ld_ag(flg + (tid & 31));
    unsigned v0 = __shfl(v, 0);
    fast = __all(v == v0);
  }

  u64* actT = act_base + (size_t)team*4096;   // [0,2048): 2 refine bufs; [2048,3072): GRU ring
  u64* gb   = actT + 2048;
  unsigned kst = 0;
  const bool wr0 = (j == 0);

  // GRU produce for step `step` (reads xst = x(step), st_h = h(step-1)):
  // publishes {f16 n_gate, f16 z_gate, tag=step+1} into gb slot (step&1).
  auto gru_produce = [&](int step){
    const unsigned gt = (unsigned)step + 1u;
    u64* g = gb + (size_t)(step & 1)*512;
    const int u = tid>>4, kk = tid&15, r = u&7;
    { // pass1: u<8 r-rows, u>=8 z-rows; K=512=[x|h]
      const float* wr = wgRZ[u];
      float a0=0.f, a1=0.f;
      #pragma unroll
      for (int i=0;i<16;i++){
        const float w = wr[kk+16*i];
        a0 += w*xst[0][kk+16*i];
        a1 += w*xst[1][kk+16*i];
      }
      #pragma unroll
      for (int i=0;i<16;i++){
        const float w = wr[256+kk+16*i];
        a0 += w*st_h[0][kk+16*i];
        a1 += w*st_h[1][kk+16*i];
      }
      a0 += __shfl_xor(a0,1); a0 += __shfl_xor(a0,2); a0 += __shfl_xor(a0,4); a0 += __shfl_xor(a0,8);
      a1 += __shfl_xor(a1,1); a1 += __shfl_xor(a1,2); a1 += __shfl_xor(a1,4); a1 += __shfl_xor(a1,8);
      if (kk==0){ exvC[u][0] = a0; exvC[u][1] = a1; }
    }
    { // pass2: u<8 xn rows (src=x), u>=8 hn rows (src=h); K=256
      const bool isH = (u>=8);
      const float* wr = isH? wgN[r] : wgX[r];
      float (*src)[256] = isH? st_h : xst;
      float a0=0.f, a1=0.f;
      #pragma unroll
      for (int i=0;i<16;i++){
        const float w = wr[kk+16*i];
        a0 += w*src[0][kk+16*i];
        a1 += w*src[1][kk+16*i];
      }
      a0 += __shfl_xor(a0,1); a0 += __shfl_xor(a0,2); a0 += __shfl_xor(a0,4); a0 += __shfl_xor(a0,8);
      a1 += __shfl_xor(a1,1); a1 += __shfl_xor(a1,2); a1 += __shfl_xor(a1,4); a1 += __shfl_xor(a1,8);
      if (kk==0){ exvD[u][0] = a0; exvD[u][1] = a1; }
    }
    WGBAR();
    if (tid < 16){
      const int b = tid&1, rr = tid>>1;
      const float pr = exvC[rr][b]   + bR[rr];
      const float pz = exvC[8+rr][b] + bZ[rr];
      const float xn = exvD[rr][b]   + bX[rr];
      const float hn = exvD[8+rr][b] + bN[rr];
      const float rg = sigf(pr);
      const float zg = sigf(pz);
      const float ng = ftanh(xn + rg*hn);
      swpw(&g[(size_t)(j*8+rr)*2 + b], packh(ng, zg, gt), fast);
    }
  };

  // C-cell: rows [8j,8j+8): units u<8 gate rows, u>=8 tanh rows. K=512=[o|hid].
  // Word layout: buf[n*2+b] = {f16 g, f16 T, tag}. pg: also produce GRU(tt+1).
  auto cstage = [&](float (*WG)[520], float (*WT)[520], float* bG, float* bT,
                    float (*hid)[256], bool wout, bool pg, int tt){
    const unsigned tag = kst + 1u;
    u64* buf = actT + (kst & 1u)*1024;
    WGBAR();                                   // prev-stage state updates visible
    const int u = tid>>4, kk = tid&15, r = u&7;
    const bool isT = (u>=8);
    const float* wr = isT? WT[r] : WG[r];
    float a0=0.f, a1=0.f;
    #pragma unroll
    for (int i=0;i<16;i++){
      const float w = wr[kk+16*i];
      a0 += w*st_o[0][kk+16*i];
      a1 += w*st_o[1][kk+16*i];
    }
    #pragma unroll
    for (int i=0;i<16;i++){
      const float w = wr[256+kk+16*i];
      a0 += w*hid[0][kk+16*i];
      a1 += w*hid[1][kk+16*i];
    }
    a0 += __shfl_xor(a0,1); a0 += __shfl_xor(a0,2); a0 += __shfl_xor(a0,4); a0 += __shfl_xor(a0,8);
    a1 += __shfl_xor(a1,1); a1 += __shfl_xor(a1,2); a1 += __shfl_xor(a1,4); a1 += __shfl_xor(a1,8);
    if (kk==0){ exvA[u][0] = a0; exvA[u][1] = a1; }
    WGBAR();
    if (tid < 16){
      const int b = tid&1, rr = tid>>1;
      const float g = sigf (exvA[rr][b]   + bG[rr]);
      const float T = ftanh(exvA[8+rr][b] + bT[rr]);
      swpw(&buf[(size_t)(j*8+rr)*2 + b], packh(g, T, tag), fast);
    }
    if (pg) gru_produce(tt+1);                 // hidden under this stage's exchange wait
    unsigned lo0, lo1;
    poll2x(&buf[2*tid], tag, fast, lo0, lo1);
    const float2 gt0 = upk2(lo0);
    const float2 gt1 = upk2(lo1);
    const float o0 = gt0.x*gt0.y + (1.f-gt0.x)*st_o[0][tid];
    const float o1 = gt1.x*gt1.y + (1.f-gt1.x)*st_o[1][tid];
    st_o[0][tid] = o0;
    st_o[1][tid] = o1;
    if (wout && wr0){
      out[((size_t)(team*BPT+0)*SEQ + tt)*256 + tid] = o0;
      out[((size_t)(team*BPT+1)*SEQ + tt)*256 + tid] = o1;
    }
    kst++;
  };

  // U-cell: 8 rows/WG, 32-lane units, K=256 over st_o; dst = tanh(pre).
  // Word per n: {f16 v_b0, f16 v_b1, tag} at buf[n].
  auto ustage = [&](float (*W)[264], float* bU, float (*dst)[256]){
    const unsigned tag = kst + 1u;
    u64* buf = actT + (kst & 1u)*1024;
    WGBAR();
    const int u = tid>>5, kk = tid&31;
    const float* wr = W[u];
    float a0=0.f, a1=0.f;
    #pragma unroll
    for (int i=0;i<8;i++){
      const float w = wr[kk+32*i];
      a0 += w*st_o[0][kk+32*i];
      a1 += w*st_o[1][kk+32*i];
    }
    a0 += __shfl_xor(a0,1); a0 += __shfl_xor(a0,2); a0 += __shfl_xor(a0,4); a0 += __shfl_xor(a0,8); a0 += __shfl_xor(a0,16);
    a1 += __shfl_xor(a1,1); a1 += __shfl_xor(a1,2); a1 += __shfl_xor(a1,4); a1 += __shfl_xor(a1,8); a1 += __shfl_xor(a1,16);
    if (kk==0){ exvA[u][0] = a0; exvA[u][1] = a1; }
    WGBAR();
    if (tid < 8){
      const float v0 = ftanh(exvA[tid][0] + bU[tid]);
      const float v1 = ftanh(exvA[tid][1] + bU[tid]);
      swpw(&buf[j*8 + tid], packh(v0, v1, tag), fast);
    }
    const unsigned lo = poll1x(&buf[tid], tag, fast);
    const float2 v = upk2(lo);
    dst[0][tid] = v.x;
    dst[1][tid] = v.y;
    kst++;
  };

  // prologue: produce GRU(0) (tag 1, slot 0) from h0 and x(0)
  float px0 = x[((size_t)(team*BPT+0)*SEQ + 1)*256 + tid];
  float px1 = x[((size_t)(team*BPT+1)*SEQ + 1)*256 + tid];
  gru_produce(0);

  #pragma unroll 1
  for (int t=0; t<SEQ; ++t){
    // ---- GRU consume (pre-satisfied poll: produced >=11 stages ago) ----
    {
      WGBAR();                                 // prior U_H matvec reads of st_o done
      u64* g = gb + (size_t)(t & 1)*512;
      unsigned lo0, lo1;
      poll2x(&g[2*tid], (unsigned)(t+1), fast, lo0, lo1);
      const float2 nz0 = upk2(lo0);
      const float2 nz1 = upk2(lo1);
      const float h0v = (1.f-nz0.y)*nz0.x + nz0.y*st_h[0][tid];
      const float h1v = (1.f-nz1.y)*nz1.x + nz1.y*st_h[1][tid];
      st_h[0][tid] = h0v;  st_o[0][tid] = h0v;
      st_h[1][tid] = h1v;  st_o[1][tid] = h1v;
      xst[0][tid] = px0;                       // x(t+1) for GRU produce at L1(t)
      xst[1][tid] = px1;
      if (t+2 < SEQ){
        px0 = x[((size_t)(team*BPT+0)*SEQ + (t+2))*256 + tid];
        px1 = x[((size_t)(team*BPT+1)*SEQ + (t+2))*256 + tid];
      }
      if (t == SEQ-1 && wr0){
        out[(size_t)NB*SEQ*256 + (team*BPT+0)*256 + tid] = h0v;
        out[(size_t)NB*SEQ*256 + (team*BPT+1)*256 + tid] = h1v;
      }
    }
    // ---- refinement: 2 H-cycles of (3x L-cell, U_L, H-cell, U_H) ----
    #pragma unroll 1
    for (int c=0;c<2;c++){
      cstage(wclG,wclT,bCLg,bCLt,st_zh,false,(c==0)&&(t+1<SEQ),t);  // L1 (+GRU(t+1))
      cstage(wclG,wclT,bCLg,bCLt,st_zh,false,false,t);
      cstage(wclG,wclT,bCLg,bCLt,st_zh,false,false,t);
      ustage(wul,bUL,st_zl);
      cstage(wchG,wchT,bCHg,bCHt,st_zl,(c==1),false,t);
      ustage(wuh,bUH,st_zh);
    }
  }
}

extern "C" void kernel_launch(void* const* d_in, const int* in_sizes, int n_in,
                              void* d_out, int out_size, void* d_ws, size_t ws_size,
                              hipStream_t stream)
{
  // ws: [0,32KB) team startup flag arrays (4KB apart); [64KB, +256KB) tagged
  // act buffers (32KB/team). Zeroed every launch (tags must start below 1).
  (void)hipMemsetAsync(d_ws, 0, 65536 + (size_t)TEAMS*4096*sizeof(u64), stream);
  unsigned* flg = (unsigned*)d_ws;
  u64* act = (u64*)((char*)d_ws + 65536);

  dim3 grid(TEAMS*WPT), block(NTH);
  hipLaunchKernelGGL(trm_kernel, grid, block, 0, stream,
    (const float*)d_in[0],  (const float*)d_in[1],
    (const float*)d_in[2],  (const float*)d_in[3],
    (const float*)d_in[4],  (const float*)d_in[5],
    (const float*)d_in[6],  (const float*)d_in[7],
    (const float*)d_in[8],  (const float*)d_in[9],
    (const float*)d_in[10], (const float*)d_in[11],
    (const float*)d_in[12], (const float*)d_in[13],
    (const float*)d_in[14], (const float*)d_in[15],
    (const float*)d_in[16], (const float*)d_in[17],
    (float*)d_out, flg, act);
}